// Round 1
// baseline (210.373 us; speedup 1.0000x reference)
//
#include <hip/hip_runtime.h>

#define NBINS 101
#define TILE 64
#define NTHREADS 256
#define NCOPIES 8
#define HPAD 104   // padded bins per histogram copy

// ---------------------------------------------------------------------------
// Kernel 1: one block per 64x64 upper-triangular tile of the similarity
// matrix. Stages feature rows in LDS, computes 4x4 register-tiled fp32 dot
// products, bins each pair (i<j) into per-wave/lane-parity LDS histograms
// (pos = same class, neg = different class), then merges into global bins.
// ---------------------------------------------------------------------------
__global__ __launch_bounds__(NTHREADS, 2)
void hist_pairs_kernel(const float* __restrict__ feats,
                       const int* __restrict__ classes,
                       float* __restrict__ g_hist,   // [2][NBINS] global bins
                       int ntiles) {
    __shared__ float As[TILE][132];           // 64 x 128, stride 132 (pad)
    __shared__ float Bs[TILE][132];
    __shared__ float lhist[NCOPIES][2][HPAD]; // replicated pos/neg histograms
    __shared__ int clsA[TILE], clsB[TILE];

    // map blockIdx.x -> (ti, tj) with ti <= tj (row-major upper triangle)
    int b = blockIdx.x;
    int ti = 0;
    int rem = b;
    while (rem >= ntiles - ti) { rem -= (ntiles - ti); ++ti; }
    int tj = ti + rem;

    const int i0 = ti * TILE;
    const int j0 = tj * TILE;
    const int tid = threadIdx.x;

    // zero local histograms
    for (int t = tid; t < NCOPIES * 2 * HPAD; t += NTHREADS)
        ((float*)lhist)[t] = 0.0f;

    // stage A and B tiles: 64 rows x 128 cols each, float4 loads
    for (int t = tid; t < TILE * 32; t += NTHREADS) {
        int r = t >> 5;          // row 0..63
        int c = (t & 31) << 2;   // float col 0..124 step 4
        float4 va = *(const float4*)&feats[(size_t)(i0 + r) * 128 + c];
        *(float4*)&As[r][c] = va;
        float4 vb = *(const float4*)&feats[(size_t)(j0 + r) * 128 + c];
        *(float4*)&Bs[r][c] = vb;
    }
    if (tid < TILE)            clsA[tid] = classes[i0 + tid];
    else if (tid < 2 * TILE)   clsB[tid - TILE] = classes[j0 + tid - TILE];
    __syncthreads();

    // 16x16 thread grid, each thread owns a 4x4 pair sub-tile
    const int tx = tid & 15;
    const int ty = tid >> 4;
    const int ri = ty * 4;   // local rows in A
    const int rj = tx * 4;   // local rows in B

    float acc[4][4];
    #pragma unroll
    for (int i = 0; i < 4; ++i)
        #pragma unroll
        for (int j = 0; j < 4; ++j) acc[i][j] = 0.0f;

    for (int k = 0; k < 128; k += 4) {
        float4 a[4], bb[4];
        #pragma unroll
        for (int i = 0; i < 4; ++i) a[i]  = *(const float4*)&As[ri + i][k];
        #pragma unroll
        for (int j = 0; j < 4; ++j) bb[j] = *(const float4*)&Bs[rj + j][k];
        #pragma unroll
        for (int i = 0; i < 4; ++i) {
            #pragma unroll
            for (int j = 0; j < 4; ++j) {
                acc[i][j] += a[i].x * bb[j].x + a[i].y * bb[j].y
                           + a[i].z * bb[j].z + a[i].w * bb[j].w;
            }
        }
    }

    // binning: each pair contributes weight 1 to exactly one histogram
    // (pos if same class else neg), linearly split across bins idx, idx+1.
    const int wave = tid >> 6;
    const int copy = (wave << 1) | (tid & 1);   // 8 replicas
    float* hbase = &lhist[copy][0][0];
    const bool diag = (ti == tj);

    #pragma unroll
    for (int i = 0; i < 4; ++i) {
        const int gi = i0 + ri + i;
        const int ci = clsA[ri + i];
        #pragma unroll
        for (int j = 0; j < 4; ++j) {
            const int gj = j0 + rj + j;
            if (diag && gi >= gj) continue;   // strict upper triangle
            float s = acc[i][j];
            float pos = (s + 1.0f) * 50.0f;   // (s+1)/step, step=0.02
            int idx = (int)floorf(pos);
            idx = idx < 0 ? 0 : (idx > NBINS - 1 ? NBINS - 1 : idx);
            float frac = pos - (float)idx;
            int hsel = (ci == clsB[rj + j]) ? 0 : 1;
            float* h = hbase + hsel * HPAD;
            atomicAdd(&h[idx], 1.0f - frac);
            int up = idx + 1;
            if (up > NBINS - 1) up = NBINS - 1;
            atomicAdd(&h[up], frac);
        }
    }
    __syncthreads();

    // merge replicas -> global atomic add (202 bins)
    for (int t = tid; t < 2 * NBINS; t += NTHREADS) {
        int hs = t / NBINS;
        int bin = t - hs * NBINS;
        float ssum = 0.0f;
        #pragma unroll
        for (int c = 0; c < NCOPIES; ++c) ssum += lhist[c][hs][bin];
        atomicAdd(&g_hist[t], ssum);
    }
}

// ---------------------------------------------------------------------------
// Kernel 2: normalize histograms, inclusive cumsum of pos, dot with neg.
// ---------------------------------------------------------------------------
__global__ void finalize_kernel(const float* __restrict__ g_hist,
                                float* __restrict__ out) {
    __shared__ float h[2 * NBINS];
    int tid = threadIdx.x;
    if (tid < 2 * NBINS) h[tid] = g_hist[tid];
    __syncthreads();
    if (tid == 0) {
        double sp = 0.0, sn = 0.0;
        for (int k = 0; k < NBINS; ++k) { sp += h[k]; sn += h[NBINS + k]; }
        double isp = 1.0 / sp, isn = 1.0 / sn;
        double cdf = 0.0, res = 0.0;
        for (int k = 0; k < NBINS; ++k) {
            cdf += (double)h[k] * isp;                 // inclusive cumsum of hist_pos
            res += (double)h[NBINS + k] * isn * cdf;   // dot with hist_neg
        }
        out[0] = (float)res;
    }
}

extern "C" void kernel_launch(void* const* d_in, const int* in_sizes, int n_in,
                              void* d_out, int out_size, void* d_ws, size_t ws_size,
                              hipStream_t stream) {
    const float* feats   = (const float*)d_in[0];
    const int*   classes = (const int*)d_in[1];
    float* out    = (float*)d_out;
    float* g_hist = (float*)d_ws;

    int N = in_sizes[1];                       // 4096
    int ntiles = (N + TILE - 1) / TILE;        // 64
    int nblocks = ntiles * (ntiles + 1) / 2;   // 2080

    hipMemsetAsync(d_ws, 0, 2 * NBINS * sizeof(float), stream);
    hist_pairs_kernel<<<nblocks, NTHREADS, 0, stream>>>(feats, classes, g_hist, ntiles);
    finalize_kernel<<<1, 256, 0, stream>>>(g_hist, out);
}